// Round 4
// baseline (35.344 us; speedup 1.0000x reference)
//
#include <hip/hip_runtime.h>
#include <math.h>

#define HDIM 128
#define SENT -1e30f
#define CPG  8          // chunks (blocks) per graph in k_partial
#define RECF 132        // floats per partial record: [M, L, pad, pad, P[128]]

// Wave-parallel lower_bound: smallest idx with seg[idx] >= target, in [0, N].
__device__ __forceinline__ int wave_lower_bound(const int* __restrict__ seg, int N, int target) {
    const int lane = threadIdx.x & 63;
    int lo = 0, hi = N;
    while (hi - lo > 64) {
        int len = hi - lo;
        int chunk = (len + 63) >> 6;
        int pos = lo + lane * chunk;
        int v = (pos < hi) ? seg[pos] : 0x7fffffff;
        unsigned long long bal = __ballot(v < target);
        int cnt = __popcll(bal);
        if (cnt == 0) { hi = lo; break; }
        int nlo = lo + (cnt - 1) * chunk + 1;
        int nhi = (cnt < 64) ? min(hi, lo + cnt * chunk) : hi;
        lo = nlo; hi = nhi;
    }
    int pos = lo + lane;
    int v = (pos < hi) ? seg[pos] : 0x7fffffff;
    unsigned long long bal = __ballot(v < target);
    return lo + __popcll(bal);
}

// k0: per-graph query vector ws_b = W @ s_b, plus segment bounds.
__global__ void __launch_bounds__(384)
k_prep(const float* __restrict__ s, const float* __restrict__ W,
       const int* __restrict__ seg, float* __restrict__ wsw,
       int* __restrict__ bounds, int N, int B)
{
    const int b = blockIdx.x;
    const int wave = threadIdx.x >> 6;
    const int lane = threadIdx.x & 63;
    if (wave < 4) {
        const int k = wave * 32 + (lane >> 1);   // 4 waves x 32 rows = 128
        const int g = lane & 1;                  // 2 lanes per row, 64 ch each
        const float* Wr = W + (size_t)k * HDIM + g * 64;
        const float* sr = s + (size_t)b * HDIM + g * 64;
        float p = 0.f;
        #pragma unroll
        for (int ii = 0; ii < 16; ++ii) {
            float4 wv4 = *reinterpret_cast<const float4*>(Wr + 4 * ii);
            float4 sv4 = *reinterpret_cast<const float4*>(sr + 4 * ii);
            p += wv4.x * sv4.x + wv4.y * sv4.y + wv4.z * sv4.z + wv4.w * sv4.w;
        }
        p += __shfl_xor(p, 1, 64);
        if (g == 0) wsw[(size_t)b * HDIM + k] = p;
    } else if (wave == 4) {
        int v = wave_lower_bound(seg, N, b);
        if (lane == 0) bounds[b] = v;
    } else {
        if (b == B - 1 && lane == 0) bounds[B] = N;
    }
}

// k1: per-chunk online softmax partial. One merged state (M, L, P[128]) per block.
__global__ void __launch_bounds__(256, 6)
k_partial(const float* __restrict__ x, const float* __restrict__ wsw,
          const int* __restrict__ bounds, float* __restrict__ partials)
{
    const int gblk = blockIdx.x;
    const int b    = gblk >> 3;       // graph
    const int j    = gblk & (CPG - 1);
    const int tid  = threadIdx.x;
    const int wave = tid >> 6;        // 0..3
    const int lane = tid & 63;
    const int half = lane >> 5;
    const int hl   = lane & 31;       // owns channels 4*hl..4*hl+3

    __shared__ __align__(16) float ws_lds[HDIM];
    __shared__ __align__(16) float lacc[8][HDIM];
    __shared__ float lm[8], ll[8], sscale[8];
    __shared__ float sM, sL;

    if (tid < 32)
        reinterpret_cast<float4*>(ws_lds)[tid] =
            reinterpret_cast<const float4*>(wsw + (size_t)b * HDIM)[tid];
    __syncthreads();

    const int s0 = bounds[b];
    const int e0 = bounds[b + 1];
    const int len = e0 - s0;
    const int lo = s0 + ((len * j) >> 3);
    const int hi = s0 + ((len * (j + 1)) >> 3);

    const float4 wv = *reinterpret_cast<const float4*>(ws_lds + 4 * hl);
    const float* xb = x + 4 * hl;

    float  m = SENT, l = 0.f;
    float4 acc = make_float4(0.f, 0.f, 0.f, 0.f);

    if (lo < hi) {
        const int lastc = hi - 1;
        const int rbase = 8 * wave + half;     // tile = 32 rows, wave w owns 8w..8w+7

        float4 A0, A1, A2, A3, B0, B1, B2, B3;

        #define LOAD(d0,d1,d2,d3, pp) do {                                        \
            int r0_ = (pp) + rbase,     c0_ = min(r0_, lastc);                    \
            int r1_ = (pp) + rbase + 2, c1_ = min(r1_, lastc);                    \
            int r2_ = (pp) + rbase + 4, c2_ = min(r2_, lastc);                    \
            int r3_ = (pp) + rbase + 6, c3_ = min(r3_, lastc);                    \
            d0 = *reinterpret_cast<const float4*>(xb + (size_t)c0_ * HDIM);       \
            d1 = *reinterpret_cast<const float4*>(xb + (size_t)c1_ * HDIM);       \
            d2 = *reinterpret_cast<const float4*>(xb + (size_t)c2_ * HDIM);       \
            d3 = *reinterpret_cast<const float4*>(xb + (size_t)c3_ * HDIM);       \
        } while (0)

        #define PROC(d0,d1,d2,d3, pp) do {                                        \
            float h0 = d0.x*wv.x + d0.y*wv.y + d0.z*wv.z + d0.w*wv.w;             \
            float h1 = d1.x*wv.x + d1.y*wv.y + d1.z*wv.z + d1.w*wv.w;             \
            float h2 = d2.x*wv.x + d2.y*wv.y + d2.z*wv.z + d2.w*wv.w;             \
            float h3 = d3.x*wv.x + d3.y*wv.y + d3.z*wv.z + d3.w*wv.w;             \
            _Pragma("unroll")                                                     \
            for (int off = 16; off >= 1; off >>= 1) {                             \
                h0 += __shfl_xor(h0, off, 64);                                    \
                h1 += __shfl_xor(h1, off, 64);                                    \
                h2 += __shfl_xor(h2, off, 64);                                    \
                h3 += __shfl_xor(h3, off, 64);                                    \
            }                                                                     \
            const bool v0 = (pp) + rbase     < hi, v1 = (pp) + rbase + 2 < hi;    \
            const bool v2 = (pp) + rbase + 4 < hi, v3 = (pp) + rbase + 6 < hi;    \
            h0 = v0 ? h0 : SENT; h1 = v1 ? h1 : SENT;                             \
            h2 = v2 ? h2 : SENT; h3 = v3 ? h3 : SENT;                             \
            float mn = fmaxf(fmaxf(fmaxf(fmaxf(m, h0), h1), h2), h3);             \
            float sc = __expf(m - mn);                                            \
            float e0_ = v0 ? __expf(h0 - mn) : 0.f;                               \
            float e1_ = v1 ? __expf(h1 - mn) : 0.f;                               \
            float e2_ = v2 ? __expf(h2 - mn) : 0.f;                               \
            float e3_ = v3 ? __expf(h3 - mn) : 0.f;                               \
            l = l * sc + ((e0_ + e1_) + (e2_ + e3_));                             \
            acc.x = acc.x*sc + e0_*d0.x + e1_*d1.x + e2_*d2.x + e3_*d3.x;         \
            acc.y = acc.y*sc + e0_*d0.y + e1_*d1.y + e2_*d2.y + e3_*d3.y;         \
            acc.z = acc.z*sc + e0_*d0.z + e1_*d1.z + e2_*d2.z + e3_*d3.z;         \
            acc.w = acc.w*sc + e0_*d0.w + e1_*d1.w + e2_*d2.w + e3_*d3.w;         \
            m = mn;                                                               \
        } while (0)

        LOAD(A0,A1,A2,A3, lo);
        for (int p = lo; p < hi; p += 64) {
            LOAD(B0,B1,B2,B3, p + 32);      // prefetch tile p+32
            PROC(A0,A1,A2,A3, p);           // consume tile p
            LOAD(A0,A1,A2,A3, p + 64);      // prefetch tile p+64 (clamped; maybe unused)
            if (p + 32 < hi) PROC(B0,B1,B2,B3, p + 32);
        }
        #undef LOAD
        #undef PROC
    }

    // merge 8 half-wave states -> one block state (M, L, P[])
    const int st = wave * 2 + half;
    *reinterpret_cast<float4*>(&lacc[st][4 * hl]) = acc;
    if (hl == 0) { lm[st] = m; ll[st] = l; }
    __syncthreads();

    if (wave == 0 && lane < 8) {
        float mi = lm[lane], li = ll[lane];
        float M = mi;
        M = fmaxf(M, __shfl_xor(M, 1, 64));
        M = fmaxf(M, __shfl_xor(M, 2, 64));
        M = fmaxf(M, __shfl_xor(M, 4, 64));
        float sc = (li > 0.f) ? __expf(mi - M) : 0.f;
        float d  = li * sc;
        d += __shfl_xor(d, 1, 64);
        d += __shfl_xor(d, 2, 64);
        d += __shfl_xor(d, 4, 64);
        sscale[lane] = sc;
        if (lane == 0) { sM = M; sL = d; }
    }
    __syncthreads();

    float* rec = partials + (size_t)gblk * RECF;
    if (tid < HDIM) {
        float num = 0.f;
        #pragma unroll
        for (int i = 0; i < 8; ++i) num += lacc[i][tid] * sscale[i];
        rec[4 + tid] = num;
    } else if (tid == 128) {
        rec[0] = sM; rec[1] = sL;
    }
}

// k2: merge CPG partials per graph, normalize, write out.
__global__ void __launch_bounds__(128)
k_merge(const float* __restrict__ partials, float* __restrict__ out)
{
    const int b = blockIdx.x;
    const int t = threadIdx.x;        // channel 0..127
    float mi[CPG], li[CPG];
    float M = SENT;
    #pragma unroll
    for (int i = 0; i < CPG; ++i) {
        const float* rec = partials + (size_t)(b * CPG + i) * RECF;
        mi[i] = rec[0]; li[i] = rec[1];
        M = fmaxf(M, mi[i]);
    }
    float D = 0.f, num = 0.f;
    #pragma unroll
    for (int i = 0; i < CPG; ++i) {
        float sc = (li[i] > 0.f) ? __expf(mi[i] - M) : 0.f;
        D   += li[i] * sc;
        num += partials[(size_t)(b * CPG + i) * RECF + 4 + t] * sc;
    }
    out[(size_t)b * HDIM + t] = (D > 0.f) ? (num / D) : 0.f;
}

extern "C" void kernel_launch(void* const* d_in, const int* in_sizes, int n_in,
                              void* d_out, int out_size, void* d_ws, size_t ws_size,
                              hipStream_t stream) {
    const float* s   = (const float*)d_in[0];  // [B,H]
    const float* x   = (const float*)d_in[1];  // [N,H]
    const float* W   = (const float*)d_in[2];  // [H,H]
    const int*   seg = (const int*)  d_in[3];  // [N]
    float* out = (float*)d_out;

    const int B = in_sizes[0] / HDIM;
    const int N = in_sizes[3];

    float* wsf      = (float*)d_ws;
    float* wsw      = wsf;                               // [B][128]
    float* partials = wsf + (size_t)B * HDIM;            // [B*CPG][RECF]
    int*   bounds   = (int*)(partials + (size_t)B * CPG * RECF);  // [B+1]

    k_prep   <<<B,       384, 0, stream>>>(s, W, seg, wsw, bounds, N, B);
    k_partial<<<B * CPG, 256, 0, stream>>>(x, wsw, bounds, partials);
    k_merge  <<<B,       128, 0, stream>>>(partials, out);
}